// Round 10
// baseline (768.827 us; speedup 1.0000x reference)
//
#include <hip/hip_runtime.h>
#include <hip/hip_bf16.h>
#include <hip/hip_cooperative_groups.h>

namespace cg = cooperative_groups;

#define A_DIM 200
#define F_DIM 53
#define NAF 38
#define NPHYS 15
#define R_OUT 20
#define C_OUT 1024
#define BLOCK 256
#define HPAD 40      // ushort row stride in LDS atom/h tile
#define MROWS 208
#define KP 24        // wcT k-stride (k>=20 zeroed)

typedef __attribute__((ext_vector_type(8))) short short8;
typedef __attribute__((ext_vector_type(4))) float floatx4;

__device__ __forceinline__ float bf2f(ushort u) { return __uint_as_float((uint)u << 16); }
__device__ __forceinline__ ushort f2bf(float f) {
    union { __hip_bfloat16 h; ushort u; } cv; cv.h = __float2bfloat16(f); return cv.u;
}

// Wc (20,1024) fp32 -> wcT (1024,24) bf16, k>=20 zeroed
__global__ void wc_prep(const float* __restrict__ Wc, ushort* __restrict__ wcT) {
    const int i = blockIdx.x * 256 + threadIdx.x;
    if (i >= C_OUT * KP) return;
    const int col = i / KP, k = i - col * KP;
    wcT[i] = f2bf((k < R_OUT) ? Wc[k * C_OUT + col] : 0.f);
}

// ============ cooperative pipeline: grid = 2B, 8 blocks/CU ============
// block (b, half): P1 stage own row-half + partial agg | sync |
// P2 hnei + h-MFMA own rows -> hbuf | sync | P3 main over own col-half ->
// d1 partial | sync | P4 (blocks bx<B) combine.
__global__ __launch_bounds__(BLOCK, 8) void pggcn_coop(
    const float* __restrict__ inputs,
    const int*   __restrict__ i_s,
    const float* __restrict__ W_self,
    const float* __restrict__ W_nei,
    const float* __restrict__ b_r,
    const float* __restrict__ bc,
    const float* __restrict__ W1,
    const float* __restrict__ b1,
    const float* __restrict__ W5,
    const float* __restrict__ b5,
    const float* __restrict__ W6,
    const float* __restrict__ b6,
    const float* __restrict__ W7,
    const float* __restrict__ b7,
    const ushort* __restrict__ wcT,
    float* __restrict__ aggp2,        // [B][2][40]
    float* __restrict__ d1p,          // [B][2][32]
    ushort* __restrict__ hbuf,        // [B][208][32]
    float* __restrict__ out,
    int nB)
{
    __shared__ __align__(16) ushort s_atom[112 * HPAD];   // 8960 B (atoms -> h)
    __shared__ float s_aggp[6 * NAF];
    __shared__ float s_agg[NAF];
    __shared__ float s_hnei[32];

    float* s_pool = (float*)s_atom;        // 512 f (alias, P3 only)
    float* s_red  = (float*)s_atom + 512;  // 256 f

    cg::grid_group grid = cg::this_grid();

    const int bx   = blockIdx.x;
    const int b    = (bx >= nB) ? bx - nB : bx;
    const int half = (bx >= nB) ? 1 : 0;
    const int t    = threadIdx.x;
    const int lane = t & 63;
    const int wv   = t >> 6;
    const int lr   = lane & 15;
    const int lg   = lane >> 4;
    const int ns   = i_s[b];
    const int nmt  = (ns + 15) >> 4;
    const int nmt0 = (nmt + 1) >> 1;
    const int lt0  = half ? nmt0 : 0;
    const int lt1  = half ? nmt : nmt0;
    const int ntl  = lt1 - lt0;          // this block's tiles (may be 0)
    const int nrows = ntl * 16;
    const int row0  = lt0 * 16;
    const float* in_b = inputs + (size_t)b * (A_DIM * F_DIM);
    ushort* hb = hbuf + (size_t)b * (MROWS * 32);

    // ---- W_self B-frags; B layout col=lane&15, k=(lane>>4)*8+j ----
    short8 bws0[2], bws1[2];
    #pragma unroll
    for (int nt = 0; nt < 2; ++nt) {
        const int c = nt * 16 + lr;
        const bool cv_ = (c < R_OUT);
        #pragma unroll
        for (int j = 0; j < 8; ++j) {
            const int k0 = lg * 8 + j;
            const int k1 = 32 + lg * 8 + j;
            bws0[nt][j] = (short)(cv_ ? f2bf(W_self[k0 * R_OUT + c]) : 0);
            bws1[nt][j] = (short)((cv_ && k1 < NAF) ? f2bf(W_self[k1 * R_OUT + c]) : 0);
        }
    }

    if (half == 0 && t < NPHYS) out[(size_t)b * 16 + 1 + t] = in_b[NAF + t];

    // ---- P1: stage own rows (bf16, zero-padded), partial agg ----
    const int tot = nrows * HPAD;
    for (int i = t; i < tot; i += BLOCK) {
        const int r = i / HPAD;
        const int f = i - r * HPAD;
        const int grow = row0 + r;
        const float v = (grow < ns && f < NAF) ? in_b[grow * F_DIM + f] : 0.f;
        s_atom[i] = f2bf(v);
    }
    __syncthreads();

    if (t < 6 * NAF) {
        const int f = t % NAF, g = t / NAF;
        float s = 0.f;
        for (int r = g; r < nrows; r += 6) s += bf2f(s_atom[r * HPAD + f]);
        s_aggp[t] = s;
    }
    __syncthreads();
    if (t < NAF) {
        float s = 0.f;
        #pragma unroll
        for (int g = 0; g < 6; ++g) s += s_aggp[g * NAF + t];
        s_agg[t] = s;
        aggp2[((size_t)b * 2 + half) * 40 + t] = s;
    }
    grid.sync();   // S1: all partial aggs visible

    // ---- P2: full agg, hnei (fp32), h-MFMA own tiles, h -> hbuf ----
    if (t < NAF) s_agg[t] += aggp2[((size_t)b * 2 + (1 - half)) * 40 + t];
    __syncthreads();
    if (t < 32) {
        float s = 0.f;
        if (t < R_OUT) {
            s = b_r[t];
            #pragma unroll
            for (int f = 0; f < NAF; ++f) s += s_agg[f] * W_nei[f * R_OUT + t];
        }
        s_hnei[t] = s;
    }
    __syncthreads();

    for (int lt = wv; lt < ntl; lt += 4) {
        const int lrow = lt * 16 + lr;
        const short8 a0 = *(const short8*)&s_atom[lrow * HPAD + lg * 8];
        short8 a1 = short8{0, 0, 0, 0, 0, 0, 0, 0};
        if (lg == 0) a1 = *(const short8*)&s_atom[lrow * HPAD + 32];
        const float hn0 = s_hnei[lr];
        const float hn1 = s_hnei[16 + lr];
        floatx4 aS0 = {hn0, hn0, hn0, hn0};
        floatx4 aS1 = {hn1, hn1, hn1, hn1};
        aS0 = __builtin_amdgcn_mfma_f32_16x16x32_bf16(a0, bws0[0], aS0, 0, 0, 0);
        aS0 = __builtin_amdgcn_mfma_f32_16x16x32_bf16(a1, bws1[0], aS0, 0, 0, 0);
        aS1 = __builtin_amdgcn_mfma_f32_16x16x32_bf16(a0, bws0[1], aS1, 0, 0, 0);
        aS1 = __builtin_amdgcn_mfma_f32_16x16x32_bf16(a1, bws1[1], aS1, 0, 0, 0);
        // C/D: col = lane&15, row = (lane>>4)*4 + q
        #pragma unroll
        for (int q = 0; q < 4; ++q) {
            const int lr2 = lt * 16 + lg * 4 + q;
            const bool vv = (row0 + lr2) < ns;
            s_atom[lr2 * HPAD + lr]      = vv ? f2bf(fmaxf(aS0[q], 0.f)) : (ushort)0;
            s_atom[lr2 * HPAD + 16 + lr] = vv ? f2bf(fmaxf(aS1[q], 0.f)) : (ushort)0;
        }
    }
    __syncthreads();

    {   // coalesced h copy-out: nrows x 32 ushorts (16 uints/row)
        const uint* sa_u = (const uint*)s_atom;
        uint* hb_u = (uint*)(hb + row0 * 32);
        const int n_u = nrows * 16;
        for (int i = t; i < n_u; i += BLOCK) {
            const int r = i >> 4, c = i & 15;
            hb_u[i] = sa_u[r * 20 + c];
        }
    }
    grid.sync();   // S2: all h visible

    // ---- P3: main over own col-half (512 cols, 2 quarters of 4 tiles) ----
    const float dead = (float)(nmt * 16 - ns);
    float pool[8];
    #pragma unroll
    for (int i = 0; i < 8; ++i) pool[i] = 0.f;

    #pragma unroll 1
    for (int qt = 0; qt < 2; ++qt) {
        short8 bfr[4];
        float  bcv[4];
        #pragma unroll
        for (int nt = 0; nt < 4; ++nt) {
            const int col = half * 512 + wv * 128 + qt * 64 + nt * 16 + lr;
            bcv[nt] = bc[col];
            if (lg < 3) bfr[nt] = *(const short8*)&wcT[col * KP + lg * 8];
            else        bfr[nt] = short8{0, 0, 0, 0, 0, 0, 0, 0};
        }
        for (int mt = 0; mt < nmt; ++mt) {
            const short8 af = *(const short8*)&hb[(mt * 16 + lr) * 32 + lg * 8];
            #pragma unroll
            for (int nt = 0; nt < 4; ++nt) {
                floatx4 acc = { bcv[nt], bcv[nt], bcv[nt], bcv[nt] };
                acc = __builtin_amdgcn_mfma_f32_16x16x32_bf16(af, bfr[nt], acc, 0, 0, 0);
                pool[qt * 4 + nt] += fmaxf(acc[0], 0.f) + fmaxf(acc[1], 0.f)
                                   + fmaxf(acc[2], 0.f) + fmaxf(acc[3], 0.f);
            }
        }
        if (lg == 0) {   // dead rows contributed relu(bc) each
            #pragma unroll
            for (int nt = 0; nt < 4; ++nt)
                pool[qt * 4 + nt] -= dead * fmaxf(bcv[nt], 0.f);
        }
    }
    #pragma unroll
    for (int i = 0; i < 8; ++i) {
        float p = pool[i];
        p += __shfl_xor(p, 16);
        p += __shfl_xor(p, 32);
        pool[i] = p;
    }
    __syncthreads();   // s_atom LDS dead; alias safe
    if (lg == 0) {
        #pragma unroll
        for (int qt = 0; qt < 2; ++qt)
            #pragma unroll
            for (int nt = 0; nt < 4; ++nt)
                s_pool[wv * 128 + qt * 64 + nt * 16 + lr] = pool[qt * 4 + nt];
    }
    __syncthreads();

    {   // pre-bias d1 partial over this half's 512 cols: 8 parts x 64 j
        const int m = t & 31, part = t >> 5;
        const float4* pp = (const float4*)&s_pool[part * 64];
        const float* wrow = W1 + (size_t)(half * 512 + part * 64) * 32 + m;
        float s = 0.f;
        #pragma unroll
        for (int jq = 0; jq < 16; ++jq) {
            const float4 pv = pp[jq];
            s += pv.x * wrow[0] + pv.y * wrow[32] + pv.z * wrow[64] + pv.w * wrow[96];
            wrow += 128;
        }
        s_red[part * 32 + m] = s;
    }
    __syncthreads();
    if (t < 32) {
        float s = 0.f;
        #pragma unroll
        for (int p = 0; p < 8; ++p) s += s_red[p * 32 + t];
        d1p[((size_t)b * 2 + half) * 32 + t] = s;
    }
    grid.sync();   // S3: d1 partials visible

    // ---- P4: combine (blocks bx < nB; 16 threads) ----
    if (bx < nB && t < 16) {
        const int dim = t;
        const float* wsd = d1p + (size_t)bx * 64;
        float s = b5[dim];
        #pragma unroll
        for (int m = 0; m < 32; ++m) {
            const float d1m = fmaxf(wsd[m] + wsd[32 + m] + b1[m], 0.f);
            s += d1m * W5[m * 16 + dim];
        }
        float c = fmaxf(s, 0.f) * W6[dim];
        c += __shfl_xor(c, 1);
        c += __shfl_xor(c, 2);
        c += __shfl_xor(c, 4);
        c += __shfl_xor(c, 8);
        if (dim == 0) {
            float o = b7[0] + W7[0] * (b6[0] + c);
            const float* ph = inputs + (size_t)bx * (A_DIM * F_DIM) + NAF;
            #pragma unroll
            for (int i = 0; i < NPHYS; ++i) o += W7[i + 1] * ph[i];
            out[(size_t)bx * 16] = o;
        }
    }
}

// ============ fallback tiers (R8-proven) ============
template <bool USE_WS, bool SPLIT>
__global__ __launch_bounds__(BLOCK, SPLIT ? 8 : 4) void pggcn_kernel(
    const float* __restrict__ inputs,
    const int*   __restrict__ i_s,
    const float* __restrict__ W_self,
    const float* __restrict__ W_nei,
    const float* __restrict__ b_r,
    const float* __restrict__ Wc,
    const float* __restrict__ bc,
    const float* __restrict__ W1,
    const float* __restrict__ b1,
    const float* __restrict__ W5,
    const float* __restrict__ b5,
    const float* __restrict__ W6,
    const float* __restrict__ b6,
    const float* __restrict__ W7,
    const float* __restrict__ b7,
    const ushort* __restrict__ wcT,
    float* __restrict__ d1p,
    float* __restrict__ out, int nB)
{
    __shared__ __align__(16) ushort s_hb[MROWS * HPAD];
    __shared__ float s_aggp[6 * 40];
    __shared__ float s_agg[40];
    __shared__ float s_hnei[32];
    __shared__ float s_phys[NPHYS];

    float* s_pool = (float*)s_hb;
    float* s_red  = (float*)s_hb + (SPLIT ? 512 : 1024);
    float* s_d1   = s_red + 256;
    float* s_d5   = s_d1 + 32;

    const int bx    = blockIdx.x;
    const int b     = SPLIT ? (bx >= nB ? bx - nB : bx) : bx;
    const int half0 = SPLIT ? (bx >= nB ? 1 : 0) : 0;
    const int t     = threadIdx.x;
    const int lane  = t & 63;
    const int wv    = t >> 6;
    const int lr    = lane & 15;
    const int lg    = lane >> 4;
    const int ns    = i_s[b];
    const int nmt   = (ns + 15) >> 4;
    const float* in_b = inputs + (size_t)b * (A_DIM * F_DIM);

    short8 bws0[2], bws1[2];
    #pragma unroll
    for (int nt = 0; nt < 2; ++nt) {
        const int c = nt * 16 + lr;
        const bool cv_ = (c < R_OUT);
        #pragma unroll
        for (int j = 0; j < 8; ++j) {
            const int k0 = lg * 8 + j;
            const int k1 = 32 + lg * 8 + j;
            bws0[nt][j] = (short)(cv_ ? f2bf(W_self[k0 * R_OUT + c]) : 0);
            bws1[nt][j] = (short)((cv_ && k1 < NAF) ? f2bf(W_self[k1 * R_OUT + c]) : 0);
        }
    }

    if ((!SPLIT || half0 == 0) && t < NPHYS) {
        const float p = in_b[NAF + t];
        if (!SPLIT) s_phys[t] = p;
        out[(size_t)b * 16 + 1 + t] = p;
    }

    const int tot = nmt * 16 * HPAD;
    for (int i = t; i < tot; i += BLOCK) {
        const int r = i / HPAD;
        const int f = i - r * HPAD;
        const float v = (r < ns && f < NAF) ? in_b[r * F_DIM + f] : 0.f;
        s_hb[i] = f2bf(v);
    }
    __syncthreads();

    if (t < 240) {
        const int f = t % 40, g = t / 40;
        float s = 0.f;
        for (int r = g; r < ns; r += 6) s += bf2f(s_hb[r * HPAD + f]);
        s_aggp[g * 40 + f] = s;
    }
    __syncthreads();
    if (t < 40) {
        float s = 0.f;
        #pragma unroll
        for (int g = 0; g < 6; ++g) s += s_aggp[g * 40 + t];
        s_agg[t] = s;
    }
    __syncthreads();

    if (t < 32) {
        float s = 0.f;
        if (t < R_OUT) {
            s = b_r[t];
            #pragma unroll
            for (int f = 0; f < NAF; ++f) s += s_agg[f] * W_nei[f * R_OUT + t];
        }
        s_hnei[t] = s;
    }
    __syncthreads();

    for (int mt = wv; mt < nmt; mt += 4) {
        const int ar = mt * 16 + lr;
        const short8 a0 = *(const short8*)&s_hb[ar * HPAD + lg * 8];
        short8 a1 = short8{0, 0, 0, 0, 0, 0, 0, 0};
        if (lg == 0) a1 = *(const short8*)&s_hb[ar * HPAD + 32];
        const float hn0 = s_hnei[lr];
        const float hn1 = s_hnei[16 + lr];
        floatx4 aS0 = {hn0, hn0, hn0, hn0};
        floatx4 aS1 = {hn1, hn1, hn1, hn1};
        aS0 = __builtin_amdgcn_mfma_f32_16x16x32_bf16(a0, bws0[0], aS0, 0, 0, 0);
        aS0 = __builtin_amdgcn_mfma_f32_16x16x32_bf16(a1, bws1[0], aS0, 0, 0, 0);
        aS1 = __builtin_amdgcn_mfma_f32_16x16x32_bf16(a0, bws0[1], aS1, 0, 0, 0);
        aS1 = __builtin_amdgcn_mfma_f32_16x16x32_bf16(a1, bws1[1], aS1, 0, 0, 0);
        #pragma unroll
        for (int q = 0; q < 4; ++q) {
            const int row = mt * 16 + lg * 4 + q;
            const bool v = (row < ns);
            s_hb[row * HPAD + lr]      = v ? f2bf(fmaxf(aS0[q], 0.f)) : (ushort)0;
            s_hb[row * HPAD + 16 + lr] = v ? f2bf(fmaxf(aS1[q], 0.f)) : (ushort)0;
        }
    }

    constexpr int NQ = SPLIT ? 2 : 4;
    const float dead = (float)(nmt * 16 - ns);
    float pool[NQ * 4];
    #pragma unroll
    for (int i = 0; i < NQ * 4; ++i) pool[i] = 0.f;

    #pragma unroll 1
    for (int qt = 0; qt < NQ; ++qt) {
        short8 bfr[4];
        float  bcv[4];
        #pragma unroll
        for (int nt = 0; nt < 4; ++nt) {
            const int col = half0 * 512 + wv * (SPLIT ? 128 : 256) + qt * 64 + nt * 16 + lr;
            bcv[nt] = bc[col];
            if (USE_WS) {
                if (lg < 3) bfr[nt] = *(const short8*)&wcT[col * KP + lg * 8];
                else        bfr[nt] = short8{0, 0, 0, 0, 0, 0, 0, 0};
            } else {
                #pragma unroll
                for (int j = 0; j < 8; ++j) {
                    const int k = lg * 8 + j;
                    bfr[nt][j] = (short)((k < R_OUT) ? f2bf(Wc[k * C_OUT + col]) : 0);
                }
            }
        }
        if (qt == 0) __syncthreads();

        for (int mt = 0; mt < nmt; ++mt) {
            const short8 af = *(const short8*)&s_hb[(mt * 16 + lr) * HPAD + lg * 8];
            #pragma unroll
            for (int nt = 0; nt < 4; ++nt) {
                floatx4 acc = { bcv[nt], bcv[nt], bcv[nt], bcv[nt] };
                acc = __builtin_amdgcn_mfma_f32_16x16x32_bf16(af, bfr[nt], acc, 0, 0, 0);
                pool[qt * 4 + nt] += fmaxf(acc[0], 0.f) + fmaxf(acc[1], 0.f)
                                   + fmaxf(acc[2], 0.f) + fmaxf(acc[3], 0.f);
            }
        }
        if (lg == 0) {
            #pragma unroll
            for (int nt = 0; nt < 4; ++nt)
                pool[qt * 4 + nt] -= dead * fmaxf(bcv[nt], 0.f);
        }
    }

    #pragma unroll
    for (int i = 0; i < NQ * 4; ++i) {
        float p = pool[i];
        p += __shfl_xor(p, 16);
        p += __shfl_xor(p, 32);
        pool[i] = p;
    }
    __syncthreads();
    if (lg == 0) {
        #pragma unroll
        for (int qt = 0; qt < NQ; ++qt)
            #pragma unroll
            for (int nt = 0; nt < 4; ++nt)
                s_pool[wv * (SPLIT ? 128 : 256) + qt * 64 + nt * 16 + lr] = pool[qt * 4 + nt];
    }
    __syncthreads();

    if (SPLIT) {
        {
            const int m = t & 31, part = t >> 5;
            const float4* pp = (const float4*)&s_pool[part * 64];
            const float* wrow = W1 + (size_t)(half0 * 512 + part * 64) * 32 + m;
            float s = 0.f;
            #pragma unroll
            for (int jq = 0; jq < 16; ++jq) {
                const float4 pv = pp[jq];
                s += pv.x * wrow[0] + pv.y * wrow[32] + pv.z * wrow[64] + pv.w * wrow[96];
                wrow += 128;
            }
            s_red[part * 32 + m] = s;
        }
        __syncthreads();
        if (t < 32) {
            float s = 0.f;
            #pragma unroll
            for (int p = 0; p < 8; ++p) s += s_red[p * 32 + t];
            d1p[(size_t)b * 64 + half0 * 32 + t] = s;
        }
    } else {
        {
            const int m = t & 31, part = t >> 5;
            const float4* pp = (const float4*)&s_pool[part * 128];
            const float* wrow = W1 + (size_t)(part * 128) * 32 + m;
            float s = 0.f;
            #pragma unroll
            for (int jq = 0; jq < 32; ++jq) {
                const float4 pv = pp[jq];
                s += pv.x * wrow[0] + pv.y * wrow[32] + pv.z * wrow[64] + pv.w * wrow[96];
                wrow += 128;
            }
            s_red[part * 32 + m] = s;
        }
        __syncthreads();
        if (t < 32) {
            float s = b1[t];
            #pragma unroll
            for (int p = 0; p < 8; ++p) s += s_red[p * 32 + t];
            s_d1[t] = fmaxf(s, 0.f);
        }
        __syncthreads();
        if (t < 16) {
            float s = b5[t];
            #pragma unroll
            for (int m = 0; m < 32; ++m) s += s_d1[m] * W5[m * 16 + t];
            s_d5[t] = fmaxf(s, 0.f);
        }
        __syncthreads();
        if (t == 0) {
            float mv = b6[0];
            #pragma unroll
            for (int m = 0; m < 16; ++m) mv += s_d5[m] * W6[m];
            float o = b7[0] + W7[0] * mv;
            #pragma unroll
            for (int i = 0; i < NPHYS; ++i) o += W7[i + 1] * s_phys[i];
            out[(size_t)b * 16] = o;
        }
    }
}

__global__ void pggcn_combine(
    const float* __restrict__ inputs,
    const float* __restrict__ d1p,
    const float* __restrict__ b1,
    const float* __restrict__ W5,
    const float* __restrict__ b5,
    const float* __restrict__ W6,
    const float* __restrict__ b6,
    const float* __restrict__ W7,
    const float* __restrict__ b7,
    float* __restrict__ out, int B)
{
    const int t = threadIdx.x;
    const int g = t >> 4, dim = t & 15;
    const int b = blockIdx.x * 16 + g;
    if (b >= B) return;
    const float* wsd = d1p + (size_t)b * 64;
    float s = b5[dim];
    #pragma unroll
    for (int m = 0; m < 32; ++m) {
        const float d1m = fmaxf(wsd[m] + wsd[32 + m] + b1[m], 0.f);
        s += d1m * W5[m * 16 + dim];
    }
    float c = fmaxf(s, 0.f) * W6[dim];
    c += __shfl_xor(c, 1);
    c += __shfl_xor(c, 2);
    c += __shfl_xor(c, 4);
    c += __shfl_xor(c, 8);
    if (dim == 0) {
        float o = b7[0] + W7[0] * (b6[0] + c);
        const float* ph = inputs + (size_t)b * (A_DIM * F_DIM) + NAF;
        #pragma unroll
        for (int i = 0; i < NPHYS; ++i) o += W7[i + 1] * ph[i];
        out[(size_t)b * 16] = o;
    }
}

extern "C" void kernel_launch(void* const* d_in, const int* in_sizes, int n_in,
                              void* d_out, int out_size, void* d_ws, size_t ws_size,
                              hipStream_t stream) {
    const float* inputs = (const float*)d_in[0];
    const int*   i_s    = (const int*)d_in[1];
    const float* W_self = (const float*)d_in[2];
    const float* W_nei  = (const float*)d_in[3];
    const float* b_r    = (const float*)d_in[4];
    const float* Wc     = (const float*)d_in[5];
    const float* bc     = (const float*)d_in[6];
    const float* W1     = (const float*)d_in[7];
    const float* b1     = (const float*)d_in[8];
    const float* W5     = (const float*)d_in[9];
    const float* b5     = (const float*)d_in[10];
    const float* W6     = (const float*)d_in[11];
    const float* b6     = (const float*)d_in[12];
    const float* W7     = (const float*)d_in[13];
    const float* b7     = (const float*)d_in[14];
    float* out = (float*)d_out;

    int B = in_sizes[1];   // 1024
    const size_t off_wct  = 0;
    const size_t wct_b    = (size_t)C_OUT * KP * sizeof(ushort);        // 49152
    const size_t off_aggp = off_wct + wct_b;
    const size_t aggp_b   = (size_t)B * 2 * 40 * sizeof(float);
    const size_t off_d1p  = off_aggp + aggp_b;
    const size_t d1p_b    = (size_t)B * 2 * 32 * sizeof(float);
    const size_t off_hbuf = off_d1p + d1p_b;
    const size_t hbuf_b   = (size_t)B * MROWS * 32 * sizeof(ushort);
    const size_t need_coop = off_hbuf + hbuf_b;

    ushort* wcT   = (ushort*)((char*)d_ws + off_wct);
    float*  aggp2 = (float*)((char*)d_ws + off_aggp);
    float*  d1p   = (float*)((char*)d_ws + off_d1p);
    ushort* hbufp = (ushort*)((char*)d_ws + off_hbuf);

    if (ws_size >= need_coop) {
        wc_prep<<<(C_OUT * KP + 255) / 256, 256, 0, stream>>>(Wc, wcT);
        void* kargs[] = {
            (void*)&inputs, (void*)&i_s, (void*)&W_self, (void*)&W_nei,
            (void*)&b_r, (void*)&bc, (void*)&W1, (void*)&b1, (void*)&W5,
            (void*)&b5, (void*)&W6, (void*)&b6, (void*)&W7, (void*)&b7,
            (void*)&wcT, (void*)&aggp2, (void*)&d1p, (void*)&hbufp,
            (void*)&out, (void*)&B
        };
        hipError_t e = hipLaunchCooperativeKernel((const void*)pggcn_coop,
            dim3(2 * B), dim3(BLOCK), kargs, 0, stream);
        if (e == hipSuccess) return;
    }
    if (ws_size >= off_hbuf) {   // wcT + aggp2 + d1p fit
        wc_prep<<<(C_OUT * KP + 255) / 256, 256, 0, stream>>>(Wc, wcT);
        pggcn_kernel<true, true><<<2 * B, BLOCK, 0, stream>>>(inputs, i_s, W_self,
            W_nei, b_r, Wc, bc, W1, b1, W5, b5, W6, b6, W7, b7, wcT, d1p, out, B);
        pggcn_combine<<<(B + 15) / 16, 256, 0, stream>>>(inputs, d1p, b1, W5, b5,
            W6, b6, W7, b7, out, B);
    } else if (ws_size >= wct_b) {
        wc_prep<<<(C_OUT * KP + 255) / 256, 256, 0, stream>>>(Wc, wcT);
        pggcn_kernel<true, false><<<B, BLOCK, 0, stream>>>(inputs, i_s, W_self,
            W_nei, b_r, Wc, bc, W1, b1, W5, b5, W6, b6, W7, b7, wcT, nullptr, out, B);
    } else {
        pggcn_kernel<false, false><<<B, BLOCK, 0, stream>>>(inputs, i_s, W_self,
            W_nei, b_r, Wc, bc, W1, b1, W5, b5, W6, b6, W7, b7, nullptr, nullptr, out, B);
    }
}

// Round 11
// 61.582 us; speedup vs baseline: 12.4847x; 12.4847x over previous
//
#include <hip/hip_runtime.h>
#include <hip/hip_bf16.h>

#define A_DIM 200
#define F_DIM 53
#define NAF 38
#define NPHYS 15
#define R_OUT 20
#define C_OUT 1024
#define BLOCK 256
#define HPAD 40      // ushort row stride of LDS tile
#define MROWS 208
#define KP 24        // wcT k-stride (k>=20 zeroed)

typedef __attribute__((ext_vector_type(8))) short short8;
typedef __attribute__((ext_vector_type(4))) float floatx4;

__device__ __forceinline__ float bf2f(ushort u) { return __uint_as_float((uint)u << 16); }
__device__ __forceinline__ ushort f2bf(float f) {
    union { __hip_bfloat16 h; ushort u; } cv; cv.h = __float2bfloat16(f); return cv.u;
}

// Wc (20,1024) fp32 -> wcT (1024,24) bf16, k>=20 zeroed
__global__ void wc_prep(const float* __restrict__ Wc, ushort* __restrict__ wcT) {
    const int i = blockIdx.x * 256 + threadIdx.x;
    if (i >= C_OUT * KP) return;
    const int col = i / KP, k = i - col * KP;
    wcT[i] = f2bf((k < R_OUT) ? Wc[k * C_OUT + col] : 0.f);
}

// ===== A: per-batch agg (fp32, batched loads) -> hnei; zero d1pre; physics =====
__global__ __launch_bounds__(256, 8) void pggcn_prep(
    const float* __restrict__ inputs,
    const int*   __restrict__ i_s,
    const float* __restrict__ W_nei,
    const float* __restrict__ b_r,
    float* __restrict__ hneip,    // [B][32]
    float* __restrict__ d1pre,    // [B][32] zeroed here
    float* __restrict__ out)
{
    __shared__ float s_aggp[4 * 56];
    __shared__ float s_agg[NAF];
    const int b = blockIdx.x, t = threadIdx.x;
    const int ns = i_s[b];
    const float* in_b = inputs + (size_t)b * (A_DIM * F_DIM);

    if (t < NPHYS) out[(size_t)b * 16 + 1 + t] = in_b[NAF + t];
    if (t >= 32 && t < 64) d1pre[(size_t)b * 32 + (t - 32)] = 0.f;

    // 4 row-groups x 53 cols, 4-deep batched loads
    if (t < 4 * F_DIM) {
        const int g = t / F_DIM, c = t - g * F_DIM;
        const float* p = in_b + g * F_DIM + c;
        float s = 0.f;
        int r = g;
        for (; r + 16 <= ns; r += 16) {
            const float v0 = p[0], v1 = p[4 * F_DIM], v2 = p[8 * F_DIM], v3 = p[12 * F_DIM];
            s += (v0 + v1) + (v2 + v3);
            p += 16 * F_DIM;
        }
        for (; r < ns; r += 4) { s += *p; p += 4 * F_DIM; }
        s_aggp[g * 56 + c] = s;
    }
    __syncthreads();
    if (t < NAF) s_agg[t] = (s_aggp[t] + s_aggp[56 + t]) + (s_aggp[112 + t] + s_aggp[168 + t]);
    __syncthreads();
    if (t < 32) {
        float s = 0.f;
        if (t < R_OUT) {
            s = b_r[t];
            #pragma unroll
            for (int f = 0; f < NAF; ++f) s += s_agg[f] * W_nei[f * R_OUT + t];
        }
        hneip[(size_t)b * 32 + t] = s;
    }
}

// ===== B: row-half blocks; stage -> h-MFMA (C-in = hnei) -> main -> d1 partial =====
__global__ __launch_bounds__(256, 8) void pggcn_main(
    const float* __restrict__ inputs,
    const int*   __restrict__ i_s,
    const float* __restrict__ W_self,
    const float* __restrict__ bc,
    const float* __restrict__ W1,
    const ushort* __restrict__ wcT,
    const float* __restrict__ hneip,
    float* __restrict__ d1pre,
    int nB)
{
    __shared__ __align__(16) ushort s_hb[112 * HPAD];   // 8960 B (atoms -> h in place)

    // aliases (used only after all s_hb reads complete)
    float* s_pool = (float*)s_hb;          // 1024 f
    float* s_red  = (float*)s_hb + 1024;   // wait: 8960B = 2240 f -> 1024+256 fits? 1280 < 2240 OK
    // s_red at +1024 (256 f)

    const int bx   = blockIdx.x;
    const int b    = (bx >= nB) ? bx - nB : bx;
    const int half = (bx >= nB) ? 1 : 0;
    const int t    = threadIdx.x;
    const int lane = t & 63;
    const int wv   = t >> 6;
    const int lr   = lane & 15;
    const int lg   = lane >> 4;
    const int ns   = i_s[b];
    const int nmt  = (ns + 15) >> 4;
    const int nmt0 = (nmt + 1) >> 1;
    const int lt0  = half ? nmt0 : 0;
    const int ntl  = (half ? nmt : nmt0) - lt0;
    if (ntl <= 0) return;                 // block-uniform; no barriers crossed
    const int row0  = lt0 * 16;
    const int nrows = ntl * 16;
    const float* in_b = inputs + (size_t)b * (A_DIM * F_DIM);

    // hnei prefetch (L2-hot)
    const float hn0 = hneip[(size_t)b * 32 + lr];
    const float hn1 = hneip[(size_t)b * 32 + 16 + lr];

    // W_self B-frags; B layout col=lane&15, k=(lane>>4)*8+j
    short8 bws0[2], bws1[2];
    #pragma unroll
    for (int nt = 0; nt < 2; ++nt) {
        const int c = nt * 16 + lr;
        const bool cv_ = (c < R_OUT);
        #pragma unroll
        for (int j = 0; j < 8; ++j) {
            const int k0 = lg * 8 + j;
            const int k1 = 32 + lg * 8 + j;
            bws0[nt][j] = (short)(cv_ ? f2bf(W_self[k0 * R_OUT + c]) : 0);
            bws1[nt][j] = (short)((cv_ && k1 < NAF) ? f2bf(W_self[k1 * R_OUT + c]) : 0);
        }
    }

    // ---- stage own rows bf16, 8-deep batched loads (f>=NAF / rows>=ns zeroed) ----
    const int tot = nrows * HPAD;   // <= 4480
    for (int base = 0; base < tot; base += BLOCK * 8) {
        float v[8];
        #pragma unroll
        for (int u = 0; u < 8; ++u) {
            const int i = base + u * BLOCK + t;
            v[u] = 0.f;
            if (i < tot) {
                const int r = i / HPAD;
                const int f = i - r * HPAD;
                const int grow = row0 + r;
                if (grow < ns && f < NAF) v[u] = in_b[grow * F_DIM + f];
            }
        }
        #pragma unroll
        for (int u = 0; u < 8; ++u) {
            const int i = base + u * BLOCK + t;
            if (i < tot) s_hb[i] = f2bf(v[u]);
        }
    }
    __syncthreads();

    // ---- h-MFMA in place: h = (row<ns) ? relu(atom@W_self + hnei) : 0 ----
    for (int lt = wv; lt < ntl; lt += 4) {
        const int ar = lt * 16 + lr;
        const short8 a0 = *(const short8*)&s_hb[ar * HPAD + lg * 8];
        short8 a1 = short8{0, 0, 0, 0, 0, 0, 0, 0};
        if (lg == 0) a1 = *(const short8*)&s_hb[ar * HPAD + 32];
        floatx4 aS0 = {hn0, hn0, hn0, hn0};
        floatx4 aS1 = {hn1, hn1, hn1, hn1};
        aS0 = __builtin_amdgcn_mfma_f32_16x16x32_bf16(a0, bws0[0], aS0, 0, 0, 0);
        aS0 = __builtin_amdgcn_mfma_f32_16x16x32_bf16(a1, bws1[0], aS0, 0, 0, 0);
        aS1 = __builtin_amdgcn_mfma_f32_16x16x32_bf16(a0, bws0[1], aS1, 0, 0, 0);
        aS1 = __builtin_amdgcn_mfma_f32_16x16x32_bf16(a1, bws1[1], aS1, 0, 0, 0);
        // C/D: col = lane&15, row = (lane>>4)*4 + q
        #pragma unroll
        for (int q = 0; q < 4; ++q) {
            const int lrow = lt * 16 + lg * 4 + q;
            const bool vv = (row0 + lrow) < ns;
            s_hb[lrow * HPAD + lr]      = vv ? f2bf(fmaxf(aS0[q], 0.f)) : (ushort)0;
            s_hb[lrow * HPAD + 16 + lr] = vv ? f2bf(fmaxf(aS1[q], 0.f)) : (ushort)0;
        }
    }
    __syncthreads();

    // ---- main: partial pooled over own rows, ALL 1024 cols (4 quarters) ----
    const int vrows = (ns - row0 < nrows) ? (ns - row0) : nrows;
    const float dead = (float)(nrows - vrows);
    float pool[16];
    #pragma unroll
    for (int i = 0; i < 16; ++i) pool[i] = 0.f;

    #pragma unroll 1
    for (int qt = 0; qt < 4; ++qt) {
        short8 bfr[4];
        float  bcv[4];
        #pragma unroll
        for (int nt = 0; nt < 4; ++nt) {
            const int col = wv * 256 + qt * 64 + nt * 16 + lr;
            bcv[nt] = bc[col];
            if (lg < 3) bfr[nt] = *(const short8*)&wcT[col * KP + lg * 8];
            else        bfr[nt] = short8{0, 0, 0, 0, 0, 0, 0, 0};
        }
        for (int mt = 0; mt < ntl; ++mt) {
            const short8 af = *(const short8*)&s_hb[(mt * 16 + lr) * HPAD + lg * 8];
            #pragma unroll
            for (int nt = 0; nt < 4; ++nt) {
                floatx4 acc = { bcv[nt], bcv[nt], bcv[nt], bcv[nt] };
                acc = __builtin_amdgcn_mfma_f32_16x16x32_bf16(af, bfr[nt], acc, 0, 0, 0);
                pool[qt * 4 + nt] += fmaxf(acc[0], 0.f) + fmaxf(acc[1], 0.f)
                                   + fmaxf(acc[2], 0.f) + fmaxf(acc[3], 0.f);
            }
        }
        if (lg == 0) {   // local dead rows contributed relu(bc) each
            #pragma unroll
            for (int nt = 0; nt < 4; ++nt)
                pool[qt * 4 + nt] -= dead * fmaxf(bcv[nt], 0.f);
        }
    }
    #pragma unroll
    for (int i = 0; i < 16; ++i) {
        float p = pool[i];
        p += __shfl_xor(p, 16);
        p += __shfl_xor(p, 32);
        pool[i] = p;
    }
    __syncthreads();   // all s_hb reads done; alias safe
    if (lg == 0) {
        #pragma unroll
        for (int qt = 0; qt < 4; ++qt)
            #pragma unroll
            for (int nt = 0; nt < 4; ++nt)
                s_pool[wv * 256 + qt * 64 + nt * 16 + lr] = pool[qt * 4 + nt];
    }
    __syncthreads();

    // ---- pre-bias d1 partial (linear in pooled): 8 parts x 128 j ----
    {
        const int m = t & 31, part = t >> 5;
        const float4* pp = (const float4*)&s_pool[part * 128];
        const float* wrow = W1 + (size_t)(part * 128) * 32 + m;
        float s = 0.f;
        #pragma unroll
        for (int jq = 0; jq < 32; ++jq) {
            const float4 pv = pp[jq];
            s += pv.x * wrow[0] + pv.y * wrow[32] + pv.z * wrow[64] + pv.w * wrow[96];
            wrow += 128;
        }
        s_red[part * 32 + m] = s;
    }
    __syncthreads();
    if (t < 32) {
        float s = 0.f;
        #pragma unroll
        for (int p = 0; p < 8; ++p) s += s_red[p * 32 + t];
        atomicAdd(&d1pre[(size_t)b * 32 + t], s);
    }
}

// ===== C: d1 = relu(d1pre+b1); d5; out0 (16 thr/batch, 16 batches/block) =====
__global__ void pggcn_tail(
    const float* __restrict__ inputs,
    const float* __restrict__ d1pre,
    const float* __restrict__ b1,
    const float* __restrict__ W5,
    const float* __restrict__ b5,
    const float* __restrict__ W6,
    const float* __restrict__ b6,
    const float* __restrict__ W7,
    const float* __restrict__ b7,
    float* __restrict__ out, int B)
{
    const int t = threadIdx.x;
    const int g = t >> 4, dim = t & 15;
    const int b = blockIdx.x * 16 + g;
    if (b >= B) return;
    const float* wsd = d1pre + (size_t)b * 32;
    float s = b5[dim];
    #pragma unroll
    for (int m = 0; m < 32; ++m) {
        const float d1m = fmaxf(wsd[m] + b1[m], 0.f);
        s += d1m * W5[m * 16 + dim];
    }
    float c = fmaxf(s, 0.f) * W6[dim];
    c += __shfl_xor(c, 1);
    c += __shfl_xor(c, 2);
    c += __shfl_xor(c, 4);
    c += __shfl_xor(c, 8);
    if (dim == 0) {
        float o = b7[0] + W7[0] * (b6[0] + c);
        const float* ph = inputs + (size_t)b * (A_DIM * F_DIM) + NAF;
        #pragma unroll
        for (int i = 0; i < NPHYS; ++i) o += W7[i + 1] * ph[i];
        out[(size_t)b * 16] = o;
    }
}

// ===== fallback (R8-proven, no-split full pipeline) =====
template <bool USE_WS>
__global__ __launch_bounds__(BLOCK, 4) void pggcn_kernel(
    const float* __restrict__ inputs,
    const int*   __restrict__ i_s,
    const float* __restrict__ W_self,
    const float* __restrict__ W_nei,
    const float* __restrict__ b_r,
    const float* __restrict__ Wc,
    const float* __restrict__ bc,
    const float* __restrict__ W1,
    const float* __restrict__ b1,
    const float* __restrict__ W5,
    const float* __restrict__ b5,
    const float* __restrict__ W6,
    const float* __restrict__ b6,
    const float* __restrict__ W7,
    const float* __restrict__ b7,
    const ushort* __restrict__ wcT,
    float* __restrict__ out)
{
    __shared__ __align__(16) ushort s_hb[MROWS * HPAD];
    __shared__ float s_aggp[6 * 40];
    __shared__ float s_agg[40];
    __shared__ float s_hnei[32];
    __shared__ float s_phys[NPHYS];

    float* s_pool = (float*)s_hb;
    float* s_red  = (float*)s_hb + 1024;
    float* s_d1   = s_red + 256;
    float* s_d5   = s_d1 + 32;

    const int b    = blockIdx.x;
    const int t    = threadIdx.x;
    const int lane = t & 63;
    const int wv   = t >> 6;
    const int lr   = lane & 15;
    const int lg   = lane >> 4;
    const int ns   = i_s[b];
    const int nmt  = (ns + 15) >> 4;
    const float* in_b = inputs + (size_t)b * (A_DIM * F_DIM);

    short8 bws0[2], bws1[2];
    #pragma unroll
    for (int nt = 0; nt < 2; ++nt) {
        const int c = nt * 16 + lr;
        const bool cv_ = (c < R_OUT);
        #pragma unroll
        for (int j = 0; j < 8; ++j) {
            const int k0 = lg * 8 + j;
            const int k1 = 32 + lg * 8 + j;
            bws0[nt][j] = (short)(cv_ ? f2bf(W_self[k0 * R_OUT + c]) : 0);
            bws1[nt][j] = (short)((cv_ && k1 < NAF) ? f2bf(W_self[k1 * R_OUT + c]) : 0);
        }
    }

    if (t < NPHYS) {
        const float p = in_b[NAF + t];
        s_phys[t] = p;
        out[(size_t)b * 16 + 1 + t] = p;
    }

    const int tot = nmt * 16 * HPAD;
    for (int i = t; i < tot; i += BLOCK) {
        const int r = i / HPAD;
        const int f = i - r * HPAD;
        const float v = (r < ns && f < NAF) ? in_b[r * F_DIM + f] : 0.f;
        s_hb[i] = f2bf(v);
    }
    __syncthreads();

    if (t < 240) {
        const int f = t % 40, g = t / 40;
        float s = 0.f;
        for (int r = g; r < ns; r += 6) s += bf2f(s_hb[r * HPAD + f]);
        s_aggp[g * 40 + f] = s;
    }
    __syncthreads();
    if (t < 40) {
        float s = 0.f;
        #pragma unroll
        for (int g = 0; g < 6; ++g) s += s_aggp[g * 40 + t];
        s_agg[t] = s;
    }
    __syncthreads();
    if (t < 32) {
        float s = 0.f;
        if (t < R_OUT) {
            s = b_r[t];
            #pragma unroll
            for (int f = 0; f < NAF; ++f) s += s_agg[f] * W_nei[f * R_OUT + t];
        }
        s_hnei[t] = s;
    }
    __syncthreads();

    for (int mt = wv; mt < nmt; mt += 4) {
        const int ar = mt * 16 + lr;
        const short8 a0 = *(const short8*)&s_hb[ar * HPAD + lg * 8];
        short8 a1 = short8{0, 0, 0, 0, 0, 0, 0, 0};
        if (lg == 0) a1 = *(const short8*)&s_hb[ar * HPAD + 32];
        const float hn0 = s_hnei[lr];
        const float hn1 = s_hnei[16 + lr];
        floatx4 aS0 = {hn0, hn0, hn0, hn0};
        floatx4 aS1 = {hn1, hn1, hn1, hn1};
        aS0 = __builtin_amdgcn_mfma_f32_16x16x32_bf16(a0, bws0[0], aS0, 0, 0, 0);
        aS0 = __builtin_amdgcn_mfma_f32_16x16x32_bf16(a1, bws1[0], aS0, 0, 0, 0);
        aS1 = __builtin_amdgcn_mfma_f32_16x16x32_bf16(a0, bws0[1], aS1, 0, 0, 0);
        aS1 = __builtin_amdgcn_mfma_f32_16x16x32_bf16(a1, bws1[1], aS1, 0, 0, 0);
        #pragma unroll
        for (int q = 0; q < 4; ++q) {
            const int row = mt * 16 + lg * 4 + q;
            const bool v = (row < ns);
            s_hb[row * HPAD + lr]      = v ? f2bf(fmaxf(aS0[q], 0.f)) : (ushort)0;
            s_hb[row * HPAD + 16 + lr] = v ? f2bf(fmaxf(aS1[q], 0.f)) : (ushort)0;
        }
    }

    const float dead = (float)(nmt * 16 - ns);
    float pool[16];
    #pragma unroll
    for (int i = 0; i < 16; ++i) pool[i] = 0.f;

    #pragma unroll 1
    for (int qt = 0; qt < 4; ++qt) {
        short8 bfr[4];
        float  bcv[4];
        #pragma unroll
        for (int nt = 0; nt < 4; ++nt) {
            const int col = wv * 256 + qt * 64 + nt * 16 + lr;
            bcv[nt] = bc[col];
            if (USE_WS) {
                if (lg < 3) bfr[nt] = *(const short8*)&wcT[col * KP + lg * 8];
                else        bfr[nt] = short8{0, 0, 0, 0, 0, 0, 0, 0};
            } else {
                #pragma unroll
                for (int j = 0; j < 8; ++j) {
                    const int k = lg * 8 + j;
                    bfr[nt][j] = (short)((k < R_OUT) ? f2bf(Wc[k * C_OUT + col]) : 0);
                }
            }
        }
        if (qt == 0) __syncthreads();

        for (int mt = 0; mt < nmt; ++mt) {
            const short8 af = *(const short8*)&s_hb[(mt * 16 + lr) * HPAD + lg * 8];
            #pragma unroll
            for (int nt = 0; nt < 4; ++nt) {
                floatx4 acc = { bcv[nt], bcv[nt], bcv[nt], bcv[nt] };
                acc = __builtin_amdgcn_mfma_f32_16x16x32_bf16(af, bfr[nt], acc, 0, 0, 0);
                pool[qt * 4 + nt] += fmaxf(acc[0], 0.f) + fmaxf(acc[1], 0.f)
                                   + fmaxf(acc[2], 0.f) + fmaxf(acc[3], 0.f);
            }
        }
        if (lg == 0) {
            #pragma unroll
            for (int nt = 0; nt < 4; ++nt)
                pool[qt * 4 + nt] -= dead * fmaxf(bcv[nt], 0.f);
        }
    }

    #pragma unroll
    for (int i = 0; i < 16; ++i) {
        float p = pool[i];
        p += __shfl_xor(p, 16);
        p += __shfl_xor(p, 32);
        pool[i] = p;
    }
    __syncthreads();
    if (lg == 0) {
        #pragma unroll
        for (int qt = 0; qt < 4; ++qt)
            #pragma unroll
            for (int nt = 0; nt < 4; ++nt)
                s_pool[wv * 256 + qt * 64 + nt * 16 + lr] = pool[qt * 4 + nt];
    }
    __syncthreads();

    {
        const int m = t & 31, part = t >> 5;
        const float4* pp = (const float4*)&s_pool[part * 128];
        const float* wrow = W1 + (size_t)(part * 128) * 32 + m;
        float s = 0.f;
        #pragma unroll
        for (int jq = 0; jq < 32; ++jq) {
            const float4 pv = pp[jq];
            s += pv.x * wrow[0] + pv.y * wrow[32] + pv.z * wrow[64] + pv.w * wrow[96];
            wrow += 128;
        }
        s_red[part * 32 + m] = s;
    }
    __syncthreads();
    if (t < 32) {
        float s = b1[t];
        #pragma unroll
        for (int p = 0; p < 8; ++p) s += s_red[p * 32 + t];
        s_d1[t] = fmaxf(s, 0.f);
    }
    __syncthreads();
    if (t < 16) {
        float s = b5[t];
        #pragma unroll
        for (int m = 0; m < 32; ++m) s += s_d1[m] * W5[m * 16 + t];
        s_d5[t] = fmaxf(s, 0.f);
    }
    __syncthreads();
    if (t == 0) {
        float mv = b6[0];
        #pragma unroll
        for (int m = 0; m < 16; ++m) mv += s_d5[m] * W6[m];
        float o = b7[0] + W7[0] * mv;
        #pragma unroll
        for (int i = 0; i < NPHYS; ++i) o += W7[i + 1] * s_phys[i];
        out[(size_t)b * 16] = o;
    }
}

extern "C" void kernel_launch(void* const* d_in, const int* in_sizes, int n_in,
                              void* d_out, int out_size, void* d_ws, size_t ws_size,
                              hipStream_t stream) {
    const float* inputs = (const float*)d_in[0];
    const int*   i_s    = (const int*)d_in[1];
    const float* W_self = (const float*)d_in[2];
    const float* W_nei  = (const float*)d_in[3];
    const float* b_r    = (const float*)d_in[4];
    const float* Wc     = (const float*)d_in[5];
    const float* bc     = (const float*)d_in[6];
    const float* W1     = (const float*)d_in[7];
    const float* b1     = (const float*)d_in[8];
    const float* W5     = (const float*)d_in[9];
    const float* b5     = (const float*)d_in[10];
    const float* W6     = (const float*)d_in[11];
    const float* b6     = (const float*)d_in[12];
    const float* W7     = (const float*)d_in[13];
    const float* b7     = (const float*)d_in[14];
    float* out = (float*)d_out;

    const int B = in_sizes[1];   // 1024
    const size_t off_wct   = 0;
    const size_t wct_b     = (size_t)C_OUT * KP * sizeof(ushort);   // 49152
    const size_t off_hnei  = off_wct + wct_b;
    const size_t hnei_b    = (size_t)B * 32 * sizeof(float);
    const size_t off_d1pre = off_hnei + hnei_b;
    const size_t d1pre_b   = (size_t)B * 32 * sizeof(float);
    const size_t need      = off_d1pre + d1pre_b;

    ushort* wcT   = (ushort*)((char*)d_ws + off_wct);
    float*  hneip = (float*)((char*)d_ws + off_hnei);
    float*  d1pre = (float*)((char*)d_ws + off_d1pre);

    if (ws_size >= need) {
        wc_prep<<<(C_OUT * KP + 255) / 256, 256, 0, stream>>>(Wc, wcT);
        pggcn_prep<<<B, BLOCK, 0, stream>>>(inputs, i_s, W_nei, b_r, hneip, d1pre, out);
        pggcn_main<<<2 * B, BLOCK, 0, stream>>>(inputs, i_s, W_self, bc, W1, wcT,
                                                hneip, d1pre, B);
        pggcn_tail<<<(B + 15) / 16, 256, 0, stream>>>(inputs, d1pre, b1, W5, b5,
                                                      W6, b6, W7, b7, out, B);
    } else if (ws_size >= wct_b) {
        wc_prep<<<(C_OUT * KP + 255) / 256, 256, 0, stream>>>(Wc, wcT);
        pggcn_kernel<true><<<B, BLOCK, 0, stream>>>(inputs, i_s, W_self, W_nei, b_r,
            Wc, bc, W1, b1, W5, b5, W6, b6, W7, b7, wcT, out);
    } else {
        pggcn_kernel<false><<<B, BLOCK, 0, stream>>>(inputs, i_s, W_self, W_nei, b_r,
            Wc, bc, W1, b1, W5, b5, W6, b6, W7, b7, nullptr, out);
    }
}